// Round 3
// baseline (530.631 us; speedup 1.0000x reference)
//
#include <hip/hip_runtime.h>

#define NN 50000
#define EE 800000
#define DD 128
#define RR 8
#define SLOTS 9       // 8 rels + root/self
#define KSTACK 1152   // SLOTS*DD
#define NR2 (NN * RR) // 400000

typedef __attribute__((ext_vector_type(8))) short bf16x8;
typedef __attribute__((ext_vector_type(4))) float f32x4;

__device__ inline float bf2f(ushort u) {
    union { uint i; float f; } v; v.i = ((uint)u) << 16; return v.f;
}
__device__ inline ushort f2bf(float f) {
    uint b = __float_as_uint(f);
    uint r = (b + 0x7fffu + ((b >> 16) & 1u)) >> 16;
    return (ushort)r;
}

// wT[c][i], c = s*128+o: s<8 -> sum_b comp[s,b]*basis[b,i,o]; s==8 -> root[i][o].
__global__ void k_build_w(const float* __restrict__ basis, const float* __restrict__ comp,
                          const float* __restrict__ root, ushort* __restrict__ wT) {
    int idx = blockIdx.x * 256 + threadIdx.x;
    if (idx >= KSTACK * DD) return;
    int c = idx >> 7, i = idx & 127;
    int s = c >> 7, o = c & 127;
    float val;
    if (s < RR) {
        float acc = 0.f;
        #pragma unroll
        for (int b = 0; b < 8; ++b) acc += comp[s * 8 + b] * basis[(b * 128 + i) * 128 + o];
        val = acc;
    } else {
        val = root[i * 128 + o];
    }
    wT[idx] = f2bf(val);
}

__global__ void k_cvt_bf16(const float* __restrict__ x, ushort* __restrict__ xb, int n4) {
    int i = blockIdx.x * 256 + threadIdx.x;
    if (i < n4) {
        float4 v = ((const float4*)x)[i];
        uint2 p;
        p.x = (uint)f2bf(v.x) | ((uint)f2bf(v.y) << 16);
        p.y = (uint)f2bf(v.z) | ((uint)f2bf(v.w) << 16);
        ((uint2*)xb)[i] = p;
    }
}

__global__ void k_hist(const int* __restrict__ ei, const int* __restrict__ et,
                       int* __restrict__ deg_dr, int* __restrict__ row_cnt) {
    int e = blockIdx.x * 256 + threadIdx.x;
    if (e < EE) {
        int d = ei[EE + e], t = et[e];
        atomicAdd(&deg_dr[d * RR + t], 1);
        atomicAdd(&row_cnt[d], 1);
    }
}

__global__ void k_scan1(const int* __restrict__ cnt, int* __restrict__ bsum, int n) {
    __shared__ int s[256];
    int t = threadIdx.x;
    int i = blockIdx.x * 256 + t;
    s[t] = (i < n) ? cnt[i] : 0;
    __syncthreads();
    for (int o = 128; o > 0; o >>= 1) {
        if (t < o) s[t] += s[t + o];
        __syncthreads();
    }
    if (t == 0) bsum[blockIdx.x] = s[0];
}

__global__ void k_scan2(int* __restrict__ bsum, int nb) {
    __shared__ int s[256];
    int t = threadIdx.x;
    int v = (t < nb) ? bsum[t] : 0;
    s[t] = v;
    __syncthreads();
    for (int o = 1; o < 256; o <<= 1) {
        int u = (t >= o) ? s[t - o] : 0;
        __syncthreads();
        s[t] += u;
        __syncthreads();
    }
    if (t < nb) bsum[t] = s[t] - v;   // exclusive
}

__global__ void k_scan3(const int* __restrict__ cnt, const int* __restrict__ boff,
                        int* __restrict__ ptr, int n) {
    __shared__ int s[256];
    int t = threadIdx.x;
    int i = blockIdx.x * 256 + t;
    int v = (i < n) ? cnt[i] : 0;
    s[t] = v;
    __syncthreads();
    for (int o = 1; o < 256; o <<= 1) {
        int u = (t >= o) ? s[t - o] : 0;
        __syncthreads();
        s[t] += u;
        __syncthreads();
    }
    if (i < n) ptr[i + 1] = boff[blockIdx.x] + s[t];
    if (i == 0) ptr[0] = 0;
}

// Per edge: payload {key = src*9+rel, w = 1/deg(dst,rel)} stored at dst-sorted position.
__global__ void k_scatter(const int* __restrict__ ei, const int* __restrict__ et,
                          const int* __restrict__ row_ptr, const int* __restrict__ deg_dr,
                          int* __restrict__ cursor, int2* __restrict__ ekw) {
    int e = blockIdx.x * 256 + threadIdx.x;
    if (e < EE) {
        int s = ei[e], d = ei[EE + e], t = et[e];
        int p = row_ptr[d] + atomicAdd(&cursor[d], 1);
        int2 pk;
        pk.x = s * SLOTS + t;
        pk.y = __float_as_int(1.f / (float)deg_dr[d * RR + t]);
        ekw[p] = pk;
    }
}

// Dense transform: H[n][c] = sum_i A[n][i] * BT[c][i], bf16 out.
// Grid: x = 32-row tiles, y = 64-col groups. Block 256 = 4 waves, wave = 32r x 16c.
__global__ void __launch_bounds__(256) k_gemmH(const ushort* __restrict__ A,
                                               const ushort* __restrict__ BT,
                                               ushort* __restrict__ H) {
    int wid = threadIdx.x >> 6, lane = threadIdx.x & 63;
    int rlo = lane & 15, khi = (lane >> 4) << 3;
    int rowbase = blockIdx.x * 32;
    int colbase = blockIdx.y * 64 + wid * 16;
    int r0 = rowbase + rlo;      if (r0 > NN - 1) r0 = NN - 1;
    int r1 = rowbase + 16 + rlo; if (r1 > NN - 1) r1 = NN - 1;
    const ushort* a0p = A + (size_t)r0 * DD + khi;
    const ushort* a1p = A + (size_t)r1 * DD + khi;
    const ushort* bp  = BT + (size_t)(colbase + rlo) * DD + khi;
    f32x4 acc0 = {0.f, 0.f, 0.f, 0.f}, acc1 = {0.f, 0.f, 0.f, 0.f};
    #pragma unroll
    for (int kk = 0; kk < 4; ++kk) {
        int ko = kk * 32;
        bf16x8 b  = *(const bf16x8*)(bp + ko);
        bf16x8 a0 = *(const bf16x8*)(a0p + ko);
        bf16x8 a1 = *(const bf16x8*)(a1p + ko);
        acc0 = __builtin_amdgcn_mfma_f32_16x16x32_bf16(a0, b, acc0, 0, 0, 0);
        acc1 = __builtin_amdgcn_mfma_f32_16x16x32_bf16(a1, b, acc1, 0, 0, 0);
    }
    int col = colbase + rlo;
    int rowoff = (lane >> 4) << 2;
    #pragma unroll
    for (int f = 0; f < 2; ++f) {
        f32x4 av = f ? acc1 : acc0;
        int rb = rowbase + f * 16 + rowoff;
        #pragma unroll
        for (int rg = 0; rg < 4; ++rg) {
            int row = rb + rg;
            if (row < NN) H[(size_t)row * KSTACK + col] = f2bf(av[rg]);
        }
    }
}

// Gather-aggregate: out[n] = bias + H[n*9+8] + sum_e w_e * H[key_e].
// One wave per dst row; flat edge loop, unroll 4.
__global__ void __launch_bounds__(256) k_agg2(const ushort* __restrict__ H,
                                              const int* __restrict__ row_ptr,
                                              const int2* __restrict__ ekw,
                                              const float* __restrict__ bias,
                                              ushort* __restrict__ hout,
                                              float* __restrict__ fout) {
    int wid = threadIdx.x >> 6, lane = threadIdx.x & 63;
    int n = blockIdx.x * 4 + wid;
    if (n >= NN) return;
    int l2 = lane << 1;
    uint su = *(const uint*)(H + ((size_t)n * SLOTS + RR) * DD + l2);
    float a0 = bf2f((ushort)(su & 0xffffu));
    float a1 = bf2f((ushort)(su >> 16));
    int p = row_ptr[n], p1 = row_ptr[n + 1];
    for (; p + 4 <= p1; p += 4) {
        int2 e0 = ekw[p], e1 = ekw[p + 1], e2 = ekw[p + 2], e3 = ekw[p + 3];
        uint u0 = *(const uint*)(H + (size_t)e0.x * DD + l2);
        uint u1 = *(const uint*)(H + (size_t)e1.x * DD + l2);
        uint u2 = *(const uint*)(H + (size_t)e2.x * DD + l2);
        uint u3 = *(const uint*)(H + (size_t)e3.x * DD + l2);
        float w0 = __int_as_float(e0.y), w1 = __int_as_float(e1.y);
        float w2 = __int_as_float(e2.y), w3 = __int_as_float(e3.y);
        a0 += w0 * bf2f((ushort)(u0 & 0xffffu)) + w1 * bf2f((ushort)(u1 & 0xffffu))
            + w2 * bf2f((ushort)(u2 & 0xffffu)) + w3 * bf2f((ushort)(u3 & 0xffffu));
        a1 += w0 * bf2f((ushort)(u0 >> 16)) + w1 * bf2f((ushort)(u1 >> 16))
            + w2 * bf2f((ushort)(u2 >> 16)) + w3 * bf2f((ushort)(u3 >> 16));
    }
    for (; p < p1; ++p) {
        int2 e = ekw[p];
        uint u = *(const uint*)(H + (size_t)e.x * DD + l2);
        float w = __int_as_float(e.y);
        a0 += w * bf2f((ushort)(u & 0xffffu));
        a1 += w * bf2f((ushort)(u >> 16));
    }
    a0 += bias[l2];
    a1 += bias[l2 + 1];
    if (hout) {
        a0 = fmaxf(a0, 0.f);
        a1 = fmaxf(a1, 0.f);
        *(uint*)(hout + (size_t)n * DD + l2) = (uint)f2bf(a0) | ((uint)f2bf(a1) << 16);
    } else {
        float2 v; v.x = a0; v.y = a1;
        *(float2*)(fout + (size_t)n * DD + l2) = v;
    }
}

extern "C" void kernel_launch(void* const* d_in, const int* in_sizes, int n_in,
                              void* d_out, int out_size, void* d_ws, size_t ws_size,
                              hipStream_t stream) {
    const float* x      = (const float*)d_in[0];
    const int*   ei     = (const int*)d_in[1];
    const int*   et     = (const int*)d_in[2];
    const float* basis0 = (const float*)d_in[3];
    const float* comp0  = (const float*)d_in[4];
    const float* root0  = (const float*)d_in[5];
    const float* bias0  = (const float*)d_in[6];
    const float* basis1 = (const float*)d_in[7];
    const float* comp1  = (const float*)d_in[8];
    const float* root1  = (const float*)d_in[9];
    const float* bias1  = (const float*)d_in[10];
    float* out = (float*)d_out;

    char* ws = (char*)d_ws;
    size_t off = 0;
    auto alloc = [&](size_t bytes) -> void* {
        void* p = ws + off;
        off += (bytes + 255) & ~(size_t)255;
        return p;
    };
    int*    deg_dr  = (int*)alloc((size_t)NR2 * 4);
    int*    row_cnt = (int*)alloc((size_t)NN * 4);
    int*    cursor  = (int*)alloc((size_t)NN * 4);
    size_t zero_bytes = off;
    int*    row_ptr = (int*)alloc((size_t)(NN + 1) * 4);
    int*    bsum    = (int*)alloc(256 * 4);
    int2*   ekw     = (int2*)alloc((size_t)EE * 8);
    ushort* wT0     = (ushort*)alloc((size_t)KSTACK * DD * 2);
    ushort* wT1     = (ushort*)alloc((size_t)KSTACK * DD * 2);
    ushort* xb      = (ushort*)alloc((size_t)NN * DD * 2);   // layer-0 input; reused as h
    ushort* H       = (ushort*)alloc((size_t)NN * KSTACK * 2);
    if (off > ws_size) return;
    ushort* h = xb;   // safe alias: xb last read by layer-0 k_gemmH, h written after

    hipMemsetAsync(d_ws, 0, zero_bytes, stream);

    k_build_w<<<576, 256, 0, stream>>>(basis0, comp0, root0, wT0);
    k_build_w<<<576, 256, 0, stream>>>(basis1, comp1, root1, wT1);
    k_cvt_bf16<<<6250, 256, 0, stream>>>(x, xb, NN * DD / 4);
    k_hist<<<3125, 256, 0, stream>>>(ei, et, deg_dr, row_cnt);
    k_scan1<<<196, 256, 0, stream>>>(row_cnt, bsum, NN);
    k_scan2<<<1, 256, 0, stream>>>(bsum, 196);
    k_scan3<<<196, 256, 0, stream>>>(row_cnt, bsum, row_ptr, NN);
    k_scatter<<<3125, 256, 0, stream>>>(ei, et, row_ptr, deg_dr, cursor, ekw);

    dim3 ggrid((NN + 31) / 32, KSTACK / 64);
    // Layer 0
    k_gemmH<<<ggrid, 256, 0, stream>>>(xb, wT0, H);
    k_agg2<<<12500, 256, 0, stream>>>(H, row_ptr, ekw, bias0, h, nullptr);
    // Layer 1
    k_gemmH<<<ggrid, 256, 0, stream>>>(h, wT1, H);
    k_agg2<<<12500, 256, 0, stream>>>(H, row_ptr, ekw, bias1, nullptr, out);
}